// Round 1
// baseline (426.571 us; speedup 1.0000x reference)
//
#include <hip/hip_runtime.h>
#include <hip/hip_bf16.h>

#define DFEAT 4096

typedef __attribute__((ext_vector_type(8))) short bf16x8;
typedef __attribute__((ext_vector_type(4))) float f32x4;
typedef __attribute__((ext_vector_type(4))) float float4v;

__device__ inline unsigned short f32_to_bf16_rne(float f) {
  union { float f; unsigned u; } v; v.f = f;
  unsigned u = v.u;
  unsigned r = u + 0x7fffu + ((u >> 16) & 1u);
  return (unsigned short)(r >> 16);
}

// Wt[n][k] = psi[k] * sum_r omega[r][n] * g[r][(n-k)&4095], bf16, row-major [4096][4096]
__global__ void build_wt_kernel(const float* __restrict__ psi,
                                const float* __restrict__ omega,
                                const float* __restrict__ g,
                                unsigned short* __restrict__ Wt) {
  int n = blockIdx.x;
  float o0 = omega[n];
  float o1 = omega[DFEAT + n];
  float o2 = omega[2 * DFEAT + n];
  const float* g0 = g;
  const float* g1 = g + DFEAT;
  const float* g2 = g + 2 * DFEAT;
  for (int k = threadIdx.x; k < DFEAT; k += blockDim.x) {
    int idx = (n - k) & (DFEAT - 1);
    float w = o0 * g0[idx] + o1 * g1[idx] + o2 * g2[idx];
    w *= psi[k];
    Wt[(size_t)n * DFEAT + k] = f32_to_bf16_rne(w);
  }
}

// x (f32) -> bf16 bits, 8 elements/thread
__global__ void convert_x_kernel(const float* __restrict__ x,
                                 unsigned short* __restrict__ Xb, int n8) {
  int stride = gridDim.x * blockDim.x;
  for (int i = blockIdx.x * blockDim.x + threadIdx.x; i < n8; i += stride) {
    size_t base = (size_t)i * 8;
    float4v a = *(const float4v*)(x + base);
    float4v b = *(const float4v*)(x + base + 4);
    union { unsigned short s[8]; uint4 v; } o;
#pragma unroll
    for (int j = 0; j < 4; ++j) o.s[j] = f32_to_bf16_rne(a[j]);
#pragma unroll
    for (int j = 0; j < 4; ++j) o.s[4 + j] = f32_to_bf16_rne(b[j]);
    *(uint4*)(Xb + base) = o.v;
  }
}

#define BM 128
#define BN 128
#define BK 32

// C[M][N] = A[M][K] * B[N][K]^T + bias, bf16 inputs, f32 out
__global__ __launch_bounds__(256, 2) void gemm_kernel(
    const unsigned short* __restrict__ A,   // [M][K] bf16 bits
    const unsigned short* __restrict__ B,   // [N][K] bf16 bits (Wt)
    const float* __restrict__ bias,
    float* __restrict__ C,
    int M, int N, int K) {
  __shared__ unsigned short As[BM][BK];
  __shared__ unsigned short Bs[BN][BK];

  const int t = threadIdx.x;
  const int lane = t & 63;
  const int wave = t >> 6;
  const int wr = wave >> 1;   // 0..1
  const int wc = wave & 1;    // 0..1

  const int nbm = M / BM;     // 64
  // XCD-aware swizzle (nwg divisible by 8 -> bijective)
  int id = blockIdx.x;
  int per = gridDim.x >> 3;
  int swz = (id & 7) * per + (id >> 3);
  int bm = swz % nbm;
  int bn = swz / nbm;

  const int brow = bm * BM;
  const int bcol = bn * BN;

  f32x4 acc[4][4] = {};

  const int lr = lane & 15;
  const int lkb = (lane >> 4) * 8;   // k offset within BK

  for (int k0 = 0; k0 < K; k0 += BK) {
    // stage A,B tiles [128][32] bf16 (8192B each) via global_load_lds, 2 issues of 256 lanes x 16B
#pragma unroll
    for (int h = 0; h < 2; ++h) {
      int rt = h * 256 + t;
      int row = rt >> 2;
      int kc = (rt & 3) * 8;
      const unsigned short* ga = A + (size_t)(brow + row) * K + k0 + kc;
      const unsigned short* gb = B + (size_t)(bcol + row) * K + k0 + kc;
      unsigned short* la = &As[0][0] + (size_t)(h * 256 + wave * 64) * 8;
      unsigned short* lb = &Bs[0][0] + (size_t)(h * 256 + wave * 64) * 8;
      __builtin_amdgcn_global_load_lds((const __attribute__((address_space(1))) unsigned int*)ga,
                                       (__attribute__((address_space(3))) unsigned int*)la, 16, 0, 0);
      __builtin_amdgcn_global_load_lds((const __attribute__((address_space(1))) unsigned int*)gb,
                                       (__attribute__((address_space(3))) unsigned int*)lb, 16, 0, 0);
    }
    __syncthreads();   // drains vmcnt(0) + barrier

    bf16x8 af[4], bfr[4];
#pragma unroll
    for (int i = 0; i < 4; ++i)
      af[i] = *(const bf16x8*)&As[wr * 64 + i * 16 + lr][lkb];
#pragma unroll
    for (int j = 0; j < 4; ++j)
      bfr[j] = *(const bf16x8*)&Bs[wc * 64 + j * 16 + lr][lkb];

#pragma unroll
    for (int i = 0; i < 4; ++i)
#pragma unroll
      for (int j = 0; j < 4; ++j)
        acc[i][j] = __builtin_amdgcn_mfma_f32_16x16x32_bf16(af[i], bfr[j], acc[i][j], 0, 0, 0);

    __syncthreads();   // protect LDS before next stage
  }

  // epilogue: C/D layout col=lane&15, row=(lane>>4)*4+reg
  const int rbase = brow + wr * 64 + (lane >> 4) * 4;
  const int cbase = bcol + wc * 64 + lr;
#pragma unroll
  for (int i = 0; i < 4; ++i) {
#pragma unroll
    for (int j = 0; j < 4; ++j) {
      int col = cbase + j * 16;
      float bv = bias[col];
#pragma unroll
      for (int r = 0; r < 4; ++r) {
        C[(size_t)(rbase + i * 16 + r) * N + col] = acc[i][j][r] + bv;
      }
    }
  }
}

extern "C" void kernel_launch(void* const* d_in, const int* in_sizes, int n_in,
                              void* d_out, int out_size, void* d_ws, size_t ws_size,
                              hipStream_t stream) {
  const float* x     = (const float*)d_in[0];
  const float* psi   = (const float*)d_in[1];
  const float* omega = (const float*)d_in[2];
  const float* g     = (const float*)d_in[3];
  const float* bias  = (const float*)d_in[4];

  const int M = in_sizes[0] / DFEAT;   // 8192
  const int N = DFEAT;
  const int K = DFEAT;

  unsigned short* Wt = (unsigned short*)d_ws;                              // 32 MB
  unsigned short* Xb = (unsigned short*)((char*)d_ws + (size_t)N * K * 2); // 64 MB

  build_wt_kernel<<<DFEAT, 256, 0, stream>>>(psi, omega, g, Wt);

  int n8 = (M * K) / 8;
  convert_x_kernel<<<2048, 256, 0, stream>>>(x, Xb, n8);

  int nwg = (M / BM) * (N / BN);   // 64*32 = 2048
  gemm_kernel<<<nwg, 256, 0, stream>>>(Xb, Wt, bias, (float*)d_out, M, N, K);
}

// Round 2
// 341.753 us; speedup vs baseline: 1.2482x; 1.2482x over previous
//
#include <hip/hip_runtime.h>
#include <hip/hip_bf16.h>

#define DFEAT 4096
#define NS 128            // K slices of 32

typedef __attribute__((ext_vector_type(8))) short bf16x8;
typedef __attribute__((ext_vector_type(4))) float f32x4;
typedef __attribute__((ext_vector_type(4))) float float4v;

__device__ inline unsigned short f32_to_bf16_rne(float f) {
  union { float f; unsigned u; } v; v.f = f;
  unsigned u = v.u;
  unsigned r = u + 0x7fffu + ((u >> 16) & 1u);
  return (unsigned short)(r >> 16);
}

// Wt[n][k] = psi[k] * sum_r omega[r][n] * g[r][(n-k)&4095], bf16, row-major [4096][4096]
__global__ void build_wt_kernel(const float* __restrict__ psi,
                                const float* __restrict__ omega,
                                const float* __restrict__ g,
                                unsigned short* __restrict__ Wt) {
  int n = blockIdx.x;
  float o0 = omega[n];
  float o1 = omega[DFEAT + n];
  float o2 = omega[2 * DFEAT + n];
  const float* g0 = g;
  const float* g1 = g + DFEAT;
  const float* g2 = g + 2 * DFEAT;
  for (int k = threadIdx.x; k < DFEAT; k += blockDim.x) {
    int idx = (n - k) & (DFEAT - 1);
    float w = o0 * g0[idx] + o1 * g1[idx] + o2 * g2[idx];
    w *= psi[k];
    Wt[(size_t)n * DFEAT + k] = f32_to_bf16_rne(w);
  }
}

// x (f32) -> bf16 bits, 8 elements/thread
__global__ void convert_x_kernel(const float* __restrict__ x,
                                 unsigned short* __restrict__ Xb, int n8) {
  int stride = gridDim.x * blockDim.x;
  for (int i = blockIdx.x * blockDim.x + threadIdx.x; i < n8; i += stride) {
    size_t base = (size_t)i * 8;
    float4v a = *(const float4v*)(x + base);
    float4v b = *(const float4v*)(x + base + 4);
    union { unsigned short s[8]; uint4 v; } o;
#pragma unroll
    for (int j = 0; j < 4; ++j) o.s[j] = f32_to_bf16_rne(a[j]);
#pragma unroll
    for (int j = 0; j < 4; ++j) o.s[4 + j] = f32_to_bf16_rne(b[j]);
    *(uint4*)(Xb + base) = o.v;
  }
}

// Stage one 256x32 bf16 slice (A or B) of K-slice s into LDS slot, linear dest,
// pre-swizzled (inverse-XOR) global source. 2 x global_load_lds(16B) per thread.
__device__ __forceinline__ void stage(const unsigned short* __restrict__ G,
                                      unsigned short* dstbase,
                                      int baseRow, int s, int t, int wave) {
#pragma unroll
  for (int i = 0; i < 2; ++i) {
    int idx = i * 512 + t;
    int row = idx >> 2;                       // 0..255
    int chunk = (idx & 3) ^ ((row >> 1) & 3); // inverse swizzle on 16B chunks
    const unsigned short* src = G + ((size_t)(baseRow + row) << 12) + (s << 5) + (chunk << 3);
    unsigned short* dst = dstbase + (size_t)(i * 512 + wave * 64) * 8;  // lane-uniform
    __builtin_amdgcn_global_load_lds((const __attribute__((address_space(1))) unsigned int*)src,
                                     (__attribute__((address_space(3))) unsigned int*)dst, 16, 0, 0);
  }
}

// C[M][4096] = A[M][4096] * B[4096][4096]^T + bias; bf16 in, f32 out.
// 256x256 tile, 8 waves, K-slice pipeline with 3-slice lookahead, counted vmcnt.
__global__ __launch_bounds__(512, 2) void gemm_kernel(
    const unsigned short* __restrict__ A,   // [M][4096] bf16 bits
    const unsigned short* __restrict__ Bm,  // [4096][4096] bf16 bits (Wt)
    const float* __restrict__ bias,
    float* __restrict__ C,
    int M) {
  __shared__ unsigned short lds[4][2][8192];   // [slot][A/B][256*32] = 128 KiB

  const int t = threadIdx.x;
  const int lane = t & 63;
  const int wave = t >> 6;
  const int wm = wave >> 2;    // 0..1
  const int wn = wave & 3;     // 0..3

  const int nbm = M >> 8;      // 32
  int id = blockIdx.x;
  int per = gridDim.x >> 3;
  int swz = (id & 7) * per + (id >> 3);   // bijective: gridDim.x % 8 == 0
  int bm = swz % nbm;
  int bn = swz / nbm;
  const int brow = bm << 8;
  const int bcol = bn << 8;

  // per-lane swizzled read base (elements) within a 256x32 LDS slice
  const int row_l = lane & 15;
  const int swzsel = (row_l >> 1) & 3;
  const int rdA = ((wm << 7) + row_l) * 32 + (((lane >> 4) ^ swzsel) << 3);
  const int rdB = ((wn << 6) + row_l) * 32 + (((lane >> 4) ^ swzsel) << 3);

  f32x4 acc[8][4] = {};

  // prologue: stage slices 0,1,2 (12 gload instrs), wait for slice 0
  stage(A,  &lds[0][0][0], brow, 0, t, wave);
  stage(Bm, &lds[0][1][0], bcol, 0, t, wave);
  stage(A,  &lds[1][0][0], brow, 1, t, wave);
  stage(Bm, &lds[1][1][0], bcol, 1, t, wave);
  stage(A,  &lds[2][0][0], brow, 2, t, wave);
  stage(Bm, &lds[2][1][0], bcol, 2, t, wave);
  asm volatile("s_waitcnt vmcnt(8)" ::: "memory");
  __builtin_amdgcn_s_barrier();

  for (int s = 0; s < NS; ++s) {
    const int p = s & 3;
    const unsigned short* As = &lds[p][0][0];
    const unsigned short* Bs = &lds[p][1][0];
    bf16x8 a[4], b[4];

    // ---- phase A: frag rows 0-3, all cols ----
#pragma unroll
    for (int i = 0; i < 4; ++i) a[i] = *(const bf16x8*)(As + rdA + i * 512);
#pragma unroll
    for (int j = 0; j < 4; ++j) b[j] = *(const bf16x8*)(Bs + rdB + j * 512);
    if (s + 3 < NS) stage(A, &lds[(s + 3) & 3][0][0], brow, s + 3, t, wave);
    __builtin_amdgcn_s_barrier();
    __builtin_amdgcn_s_setprio(1);
#pragma unroll
    for (int i = 0; i < 4; ++i)
#pragma unroll
      for (int j = 0; j < 4; ++j)
        acc[i][j] = __builtin_amdgcn_mfma_f32_16x16x32_bf16(a[i], b[j], acc[i][j], 0, 0, 0);
    __builtin_amdgcn_s_setprio(0);
    __builtin_amdgcn_s_barrier();

    // ---- phase B: frag rows 4-7, reuse b ----
#pragma unroll
    for (int i = 0; i < 4; ++i) a[i] = *(const bf16x8*)(As + rdA + (4 + i) * 512);
    if (s + 3 < NS) stage(Bm, &lds[(s + 3) & 3][1][0], bcol, s + 3, t, wave);
    __builtin_amdgcn_s_barrier();
    __builtin_amdgcn_s_setprio(1);
#pragma unroll
    for (int i = 0; i < 4; ++i)
#pragma unroll
      for (int j = 0; j < 4; ++j)
        acc[4 + i][j] = __builtin_amdgcn_mfma_f32_16x16x32_bf16(a[i], b[j], acc[4 + i][j], 0, 0, 0);
    __builtin_amdgcn_s_setprio(0);

    // counted vmcnt: ensure slice s+1 landed before next phase-A reads.
    // steady state leaves 8 gloads (2 slices' stages) in flight; tail drains.
    int rem = NS - 1 - s;
    if (rem >= 3)      asm volatile("s_waitcnt vmcnt(8)" ::: "memory");
    else if (rem == 2) asm volatile("s_waitcnt vmcnt(4)" ::: "memory");
    else if (rem == 1) asm volatile("s_waitcnt vmcnt(0)" ::: "memory");
    __builtin_amdgcn_s_barrier();
  }

  // epilogue: C/D layout col=lane&15, row=(lane>>4)*4+reg
  const int cr = (lane >> 4) << 2;
#pragma unroll
  for (int fr = 0; fr < 8; ++fr) {
    int row = brow + (wm << 7) + fr * 16 + cr;
#pragma unroll
    for (int fc = 0; fc < 4; ++fc) {
      int col = bcol + (wn << 6) + fc * 16 + (lane & 15);
      float bv = bias[col];
      float* cp = C + ((size_t)row << 12) + col;
#pragma unroll
      for (int r = 0; r < 4; ++r)
        cp[(size_t)r << 12] = acc[fr][fc][r] + bv;
    }
  }
}

extern "C" void kernel_launch(void* const* d_in, const int* in_sizes, int n_in,
                              void* d_out, int out_size, void* d_ws, size_t ws_size,
                              hipStream_t stream) {
  const float* x     = (const float*)d_in[0];
  const float* psi   = (const float*)d_in[1];
  const float* omega = (const float*)d_in[2];
  const float* g     = (const float*)d_in[3];
  const float* bias  = (const float*)d_in[4];

  const int M = in_sizes[0] / DFEAT;   // 8192
  const int N = DFEAT;
  const int K = DFEAT;

  unsigned short* Wt = (unsigned short*)d_ws;                              // 32 MB
  unsigned short* Xb = (unsigned short*)((char*)d_ws + (size_t)N * K * 2); // 64 MB

  build_wt_kernel<<<DFEAT, 256, 0, stream>>>(psi, omega, g, Wt);

  int n8 = (M * K) / 8;
  convert_x_kernel<<<2048, 256, 0, stream>>>(x, Xb, n8);

  int nwg = (M / 256) * (N / 256);   // 32*16 = 512, divisible by 8
  gemm_kernel<<<nwg, 512, 0, stream>>>(Xb, Wt, bias, (float*)d_out, M);
}

// Round 3
// 318.828 us; speedup vs baseline: 1.3379x; 1.0719x over previous
//
#include <hip/hip_runtime.h>
#include <hip/hip_bf16.h>

#define DFEAT 4096
#define NS 128            // K slices of 32

typedef __attribute__((ext_vector_type(8))) short bf16x8;
typedef __attribute__((ext_vector_type(4))) float f32x4;
typedef __attribute__((ext_vector_type(4))) float float4v;

__device__ inline unsigned short f32_to_bf16_rne(float f) {
  union { float f; unsigned u; } v; v.f = f;
  unsigned u = v.u;
  unsigned r = u + 0x7fffu + ((u >> 16) & 1u);
  return (unsigned short)(r >> 16);
}

// Wt[n][k] = psi[k] * sum_r omega[r][n] * g[r][(n-k)&4095], bf16, row-major [4096][4096]
__global__ void build_wt_kernel(const float* __restrict__ psi,
                                const float* __restrict__ omega,
                                const float* __restrict__ g,
                                unsigned short* __restrict__ Wt) {
  int n = blockIdx.x;
  float o0 = omega[n];
  float o1 = omega[DFEAT + n];
  float o2 = omega[2 * DFEAT + n];
  const float* g0 = g;
  const float* g1 = g + DFEAT;
  const float* g2 = g + 2 * DFEAT;
  for (int k = threadIdx.x; k < DFEAT; k += blockDim.x) {
    int idx = (n - k) & (DFEAT - 1);
    float w = o0 * g0[idx] + o1 * g1[idx] + o2 * g2[idx];
    w *= psi[k];
    Wt[(size_t)n * DFEAT + k] = f32_to_bf16_rne(w);
  }
}

// x (f32) -> bf16 bits, 8 elements/thread
__global__ void convert_x_kernel(const float* __restrict__ x,
                                 unsigned short* __restrict__ Xb, int n8) {
  int stride = gridDim.x * blockDim.x;
  for (int i = blockIdx.x * blockDim.x + threadIdx.x; i < n8; i += stride) {
    size_t base = (size_t)i * 8;
    float4v a = *(const float4v*)(x + base);
    float4v b = *(const float4v*)(x + base + 4);
    union { unsigned short s[8]; uint4 v; } o;
#pragma unroll
    for (int j = 0; j < 4; ++j) o.s[j] = f32_to_bf16_rne(a[j]);
#pragma unroll
    for (int j = 0; j < 4; ++j) o.s[4 + j] = f32_to_bf16_rne(b[j]);
    *(uint4*)(Xb + base) = o.v;
  }
}

// Stage one 256x32 bf16 slice (A or B) of K-slice s into LDS slot, linear dest,
// pre-swizzled (inverse-XOR) global source. 2 x global_load_lds(16B) per thread.
__device__ __forceinline__ void stage(const unsigned short* __restrict__ G,
                                      unsigned short* dstbase,
                                      int baseRow, int s, int t, int wave) {
#pragma unroll
  for (int i = 0; i < 2; ++i) {
    int idx = i * 512 + t;
    int row = idx >> 2;                       // 0..255
    int chunk = (idx & 3) ^ ((row >> 1) & 3); // inverse swizzle on 16B chunks
    const unsigned short* src = G + ((size_t)(baseRow + row) << 12) + (s << 5) + (chunk << 3);
    unsigned short* dst = dstbase + (size_t)(i * 512 + wave * 64) * 8;  // lane-uniform
    __builtin_amdgcn_global_load_lds((const __attribute__((address_space(1))) unsigned int*)src,
                                     (__attribute__((address_space(3))) unsigned int*)dst, 16, 0, 0);
  }
}

// C[M][4096] = A[M][4096] * B[4096][4096]^T + bias; bf16 in, f32 out.
// 256x256 tile, 8 waves, K-slice pipeline, reg-double-buffered fragments,
// counted vmcnt (never 0 in main loop), 1 barrier per slice.
__global__ __launch_bounds__(512, 2) void gemm_kernel(
    const unsigned short* __restrict__ A,   // [M][4096] bf16 bits
    const unsigned short* __restrict__ Bm,  // [4096][4096] bf16 bits (Wt)
    const float* __restrict__ bias,
    float* __restrict__ C,
    int M) {
  __shared__ unsigned short lds[4][2][8192];   // [slot][A/B][256*32] = 128 KiB

  const int t = threadIdx.x;
  const int lane = t & 63;
  const int wave = t >> 6;
  const int wm = wave >> 2;    // 0..1
  const int wn = wave & 3;     // 0..3

  const int nbm = M >> 8;      // 32
  int id = blockIdx.x;
  int per = gridDim.x >> 3;
  int swz = (id & 7) * per + (id >> 3);   // bijective: gridDim.x % 8 == 0
  int bm = swz % nbm;
  int bn = swz / nbm;
  const int brow = bm << 8;
  const int bcol = bn << 8;

  // per-lane swizzled read base (elements) within a 256x32 LDS slice
  const int row_l = lane & 15;
  const int swzsel = (row_l >> 1) & 3;
  const int rdA = ((wm << 7) + row_l) * 32 + (((lane >> 4) ^ swzsel) << 3);
  const int rdB = ((wn << 6) + row_l) * 32 + (((lane >> 4) ^ swzsel) << 3);

  f32x4 acc[8][4] = {};
  bf16x8 aLo[2][4], bfr[2][4], aHi[4];

  // prologue: stage slices 0,1,2 (12 gloads, slice-0 pair oldest)
  stage(A,  &lds[0][0][0], brow, 0, t, wave);
  stage(Bm, &lds[0][1][0], bcol, 0, t, wave);
  stage(A,  &lds[1][0][0], brow, 1, t, wave);
  stage(Bm, &lds[1][1][0], bcol, 1, t, wave);
  stage(A,  &lds[2][0][0], brow, 2, t, wave);
  stage(Bm, &lds[2][1][0], bcol, 2, t, wave);
  asm volatile("s_waitcnt vmcnt(8)" ::: "memory");   // slice 0 landed
  __builtin_amdgcn_s_barrier();
  {
    const unsigned short* As0 = &lds[0][0][0];
    const unsigned short* Bs0 = &lds[0][1][0];
#pragma unroll
    for (int i = 0; i < 4; ++i) aLo[0][i] = *(const bf16x8*)(As0 + rdA + i * 512);
#pragma unroll
    for (int j = 0; j < 4; ++j) bfr[0][j] = *(const bf16x8*)(Bs0 + rdB + j * 512);
  }

#define SLICE_BODY(s, CUR, NXT, DO_STAGE, VMC, DO_RD)                          \
  {                                                                            \
    const unsigned short* As_ = &lds[(s) & 3][0][0];                           \
    _Pragma("unroll")                                                          \
    for (int i = 0; i < 4; ++i)                                                \
      aHi[i] = *(const bf16x8*)(As_ + rdA + (4 + i) * 512);                    \
    __builtin_amdgcn_s_setprio(1);                                             \
    _Pragma("unroll")                                                          \
    for (int i = 0; i < 4; ++i)                                                \
      _Pragma("unroll")                                                        \
      for (int j = 0; j < 4; ++j)                                              \
        acc[i][j] = __builtin_amdgcn_mfma_f32_16x16x32_bf16(aLo[CUR][i],       \
                        bfr[CUR][j], acc[i][j], 0, 0, 0);                      \
    __builtin_amdgcn_s_setprio(0);                                             \
    asm volatile("s_waitcnt vmcnt(" #VMC ")" ::: "memory");                    \
    __builtin_amdgcn_s_barrier();                                              \
    if (DO_RD) {                                                               \
      const unsigned short* An_ = &lds[((s) + 1) & 3][0][0];                   \
      const unsigned short* Bn_ = &lds[((s) + 1) & 3][1][0];                   \
      _Pragma("unroll")                                                        \
      for (int i = 0; i < 4; ++i)                                              \
        aLo[NXT][i] = *(const bf16x8*)(An_ + rdA + i * 512);                   \
      _Pragma("unroll")                                                        \
      for (int j = 0; j < 4; ++j)                                              \
        bfr[NXT][j] = *(const bf16x8*)(Bn_ + rdB + j * 512);                   \
    }                                                                          \
    if (DO_STAGE) {                                                            \
      stage(A,  &lds[((s) + 3) & 3][0][0], brow, (s) + 3, t, wave);            \
      stage(Bm, &lds[((s) + 3) & 3][1][0], bcol, (s) + 3, t, wave);            \
    }                                                                          \
    __builtin_amdgcn_s_setprio(1);                                             \
    _Pragma("unroll")                                                          \
    for (int i = 0; i < 4; ++i)                                                \
      _Pragma("unroll")                                                        \
      for (int j = 0; j < 4; ++j)                                              \
        acc[4 + i][j] = __builtin_amdgcn_mfma_f32_16x16x32_bf16(aHi[i],        \
                          bfr[CUR][j], acc[4 + i][j], 0, 0, 0);                \
    __builtin_amdgcn_s_setprio(0);                                             \
  }

  // main loop: slices 0..NS-5 (all have s+3 < NS), steady-state vmcnt(4)
  for (int s = 0; s < NS - 4; s += 2) {
    SLICE_BODY(s,     0, 1, true, 4, true);
    SLICE_BODY(s + 1, 1, 0, true, 4, true);
  }
  // tail: slices NS-4 .. NS-1
  SLICE_BODY(NS - 4, 0, 1, true,  4, true);   // stages slice NS-1
  SLICE_BODY(NS - 3, 1, 0, false, 4, true);
  SLICE_BODY(NS - 2, 0, 1, false, 0, true);
  SLICE_BODY(NS - 1, 1, 0, false, 0, false);
#undef SLICE_BODY

  // epilogue: C/D layout col=lane&15, row=(lane>>4)*4+reg
  const int cr = (lane >> 4) << 2;
#pragma unroll
  for (int fr = 0; fr < 8; ++fr) {
    int row = brow + (wm << 7) + fr * 16 + cr;
#pragma unroll
    for (int fc = 0; fc < 4; ++fc) {
      int col = bcol + (wn << 6) + fc * 16 + (lane & 15);
      float bv = bias[col];
      float* cp = C + ((size_t)row << 12) + col;
#pragma unroll
      for (int r = 0; r < 4; ++r)
        cp[(size_t)r << 12] = acc[fr][fc][r] + bv;
    }
  }
}

extern "C" void kernel_launch(void* const* d_in, const int* in_sizes, int n_in,
                              void* d_out, int out_size, void* d_ws, size_t ws_size,
                              hipStream_t stream) {
  const float* x     = (const float*)d_in[0];
  const float* psi   = (const float*)d_in[1];
  const float* omega = (const float*)d_in[2];
  const float* g     = (const float*)d_in[3];
  const float* bias  = (const float*)d_in[4];

  const int M = in_sizes[0] / DFEAT;   // 8192
  const int N = DFEAT;
  const int K = DFEAT;

  unsigned short* Wt = (unsigned short*)d_ws;                              // 32 MB
  unsigned short* Xb = (unsigned short*)((char*)d_ws + (size_t)N * K * 2); // 64 MB

  build_wt_kernel<<<DFEAT, 256, 0, stream>>>(psi, omega, g, Wt);

  int n8 = (M * K) / 8;
  convert_x_kernel<<<2048, 256, 0, stream>>>(x, Xb, n8);

  int nwg = (M / 256) * (N / 256);   // 32*16 = 512, divisible by 8
  gemm_kernel<<<nwg, 512, 0, stream>>>(Xb, Wt, bias, (float*)d_out, M);
}

// Round 4
// 289.413 us; speedup vs baseline: 1.4739x; 1.1016x over previous
//
#include <hip/hip_runtime.h>
#include <hip/hip_bf16.h>

#define DFEAT 4096
#define NS 128            // K slices of 32

typedef __attribute__((ext_vector_type(8))) short bf16x8;
typedef __attribute__((ext_vector_type(4))) float f32x4;
typedef __attribute__((ext_vector_type(4))) float float4v;

__device__ inline unsigned short f32_to_bf16_rne(float f) {
  union { float f; unsigned u; } v; v.f = f;
  unsigned u = v.u;
  unsigned r = u + 0x7fffu + ((u >> 16) & 1u);
  return (unsigned short)(r >> 16);
}

// Wt[n][k] = psi[k] * sum_r omega[r][n] * g[r][(n-k)&4095], bf16, row-major [4096][4096]
__global__ void build_wt_kernel(const float* __restrict__ psi,
                                const float* __restrict__ omega,
                                const float* __restrict__ g,
                                unsigned short* __restrict__ Wt) {
  int n = blockIdx.x;
  float o0 = omega[n];
  float o1 = omega[DFEAT + n];
  float o2 = omega[2 * DFEAT + n];
  const float* g0 = g;
  const float* g1 = g + DFEAT;
  const float* g2 = g + 2 * DFEAT;
  for (int k = threadIdx.x; k < DFEAT; k += blockDim.x) {
    int idx = (n - k) & (DFEAT - 1);
    float w = o0 * g0[idx] + o1 * g1[idx] + o2 * g2[idx];
    w *= psi[k];
    Wt[(size_t)n * DFEAT + k] = f32_to_bf16_rne(w);
  }
}

// x (f32) -> bf16 bits, 8 elements/thread
__global__ void convert_x_kernel(const float* __restrict__ x,
                                 unsigned short* __restrict__ Xb, int n8) {
  int stride = gridDim.x * blockDim.x;
  for (int i = blockIdx.x * blockDim.x + threadIdx.x; i < n8; i += stride) {
    size_t base = (size_t)i * 8;
    float4v a = *(const float4v*)(x + base);
    float4v b = *(const float4v*)(x + base + 4);
    union { unsigned short s[8]; uint4 v; } o;
#pragma unroll
    for (int j = 0; j < 4; ++j) o.s[j] = f32_to_bf16_rne(a[j]);
#pragma unroll
    for (int j = 0; j < 4; ++j) o.s[4 + j] = f32_to_bf16_rne(b[j]);
    *(uint4*)(Xb + base) = o.v;
  }
}

// Stage one 256x32 bf16 slice (A or B) of K-slice s into LDS slot, linear dest,
// pre-swizzled (inverse-XOR) global source. 2 x global_load_lds(16B) per thread.
__device__ __forceinline__ void stage(const unsigned short* __restrict__ G,
                                      unsigned short* dstbase,
                                      int baseRow, int s, int t, int wave) {
#pragma unroll
  for (int i = 0; i < 2; ++i) {
    int idx = i * 512 + t;
    int row = idx >> 2;                       // 0..255
    int chunk = (idx & 3) ^ ((row >> 1) & 3); // inverse swizzle on 16B chunks
    const unsigned short* src = G + ((size_t)(baseRow + row) << 12) + (s << 5) + (chunk << 3);
    unsigned short* dst = dstbase + (size_t)(i * 512 + wave * 64) * 8;  // lane-uniform
    __builtin_amdgcn_global_load_lds((const __attribute__((address_space(1))) unsigned int*)src,
                                     (__attribute__((address_space(3))) unsigned int*)dst, 16, 0, 0);
  }
}

// C[M][4096] = A[M][4096] * B[4096][4096]^T + bias; bf16 in, f32 out.
// 256x256 tile, 8 waves, two phases per K-32 slice, stages issued right after
// barriers, counted vmcnt(6) (never 0 in main loop), bm-striped XCD swizzle.
__global__ __launch_bounds__(512, 2) void gemm_kernel(
    const unsigned short* __restrict__ A,   // [M][4096] bf16 bits
    const unsigned short* __restrict__ Bm,  // [4096][4096] bf16 bits (Wt)
    const float* __restrict__ bias,
    float* __restrict__ C,
    int M) {
  __shared__ unsigned short lds[4][2][8192];   // [slot][A/B][256*32] = 128 KiB

  const int t = threadIdx.x;
  const int lane = t & 63;
  const int wave = t >> 6;
  const int wm = wave >> 2;    // 0..1
  const int wn = wave & 3;     // 0..3

  int id = blockIdx.x;
  int per = gridDim.x >> 3;                 // blocks per XCD (bijective: grid % 8 == 0)
  int swz = (id & 7) * per + (id >> 3);
  // bm-stripe per XCD: each XCD owns 4 consecutive bm panels, sweeps all 16 bn
  int bm = swz >> 4;           // 0..(M/256-1)
  int bn = swz & 15;           // 0..15
  const int brow = bm << 8;
  const int bcol = bn << 8;

  // per-lane swizzled read base (elements) within a 256x32 LDS slice
  const int row_l = lane & 15;
  const int swzsel = (row_l >> 1) & 3;
  const int rdA = ((wm << 7) + row_l) * 32 + (((lane >> 4) ^ swzsel) << 3);
  const int rdB = ((wn << 6) + row_l) * 32 + (((lane >> 4) ^ swzsel) << 3);

  f32x4 acc[8][4] = {};
  bf16x8 aLo[2][4], bfr[2][4], aHi[4];

  // prologue: stage slices 0,1,2 (12 gloads, slice-0 pair oldest)
  stage(A,  &lds[0][0][0], brow, 0, t, wave);
  stage(Bm, &lds[0][1][0], bcol, 0, t, wave);
  stage(A,  &lds[1][0][0], brow, 1, t, wave);
  stage(Bm, &lds[1][1][0], bcol, 1, t, wave);
  stage(A,  &lds[2][0][0], brow, 2, t, wave);
  stage(Bm, &lds[2][1][0], bcol, 2, t, wave);
  asm volatile("s_waitcnt vmcnt(8)" ::: "memory");   // slice 0 landed (all waves, pre-barrier)
  __builtin_amdgcn_s_barrier();
  {
    const unsigned short* As0 = &lds[0][0][0];
    const unsigned short* Bs0 = &lds[0][1][0];
#pragma unroll
    for (int i = 0; i < 4; ++i) aLo[0][i] = *(const bf16x8*)(As0 + rdA + i * 512);
#pragma unroll
    for (int j = 0; j < 4; ++j) bfr[0][j] = *(const bf16x8*)(Bs0 + rdB + j * 512);
  }

  // Phase A: RD aHi(s) | barrier | STAGE A(s+3) | MM0 | vmcnt(VMC)
  // Phase B: barrier | STAGE B(s+3) | RD aLo,b(s+1) | MM1
  // vmcnt(6) pre-barrier-B guarantees slice s+1 landed (all waves) before any
  // post-barrier RD; stages post-barrier can't overwrite slots with unconsumed
  // readers (readers' MFMAs issued before those waves reached the barrier).
#define SLICE_BODY(s, CUR, NXT, STA, STB, VMC, DO_RD)                          \
  {                                                                            \
    const unsigned short* As_ = &lds[(s) & 3][0][0];                           \
    _Pragma("unroll")                                                          \
    for (int i = 0; i < 4; ++i)                                                \
      aHi[i] = *(const bf16x8*)(As_ + rdA + (4 + i) * 512);                    \
    __builtin_amdgcn_s_barrier();                                              \
    if (STA) stage(A, &lds[((s) + 3) & 3][0][0], brow, (s) + 3, t, wave);      \
    __builtin_amdgcn_s_setprio(1);                                             \
    _Pragma("unroll")                                                          \
    for (int i = 0; i < 4; ++i)                                                \
      _Pragma("unroll")                                                        \
      for (int j = 0; j < 4; ++j)                                              \
        acc[i][j] = __builtin_amdgcn_mfma_f32_16x16x32_bf16(aLo[CUR][i],       \
                        bfr[CUR][j], acc[i][j], 0, 0, 0);                      \
    __builtin_amdgcn_s_setprio(0);                                             \
    asm volatile("s_waitcnt vmcnt(" #VMC ")" ::: "memory");                    \
    __builtin_amdgcn_s_barrier();                                              \
    if (STB) stage(Bm, &lds[((s) + 3) & 3][1][0], bcol, (s) + 3, t, wave);     \
    if (DO_RD) {                                                               \
      const unsigned short* An_ = &lds[((s) + 1) & 3][0][0];                   \
      const unsigned short* Bn_ = &lds[((s) + 1) & 3][1][0];                   \
      _Pragma("unroll")                                                        \
      for (int i = 0; i < 4; ++i)                                              \
        aLo[NXT][i] = *(const bf16x8*)(An_ + rdA + i * 512);                   \
      _Pragma("unroll")                                                        \
      for (int j = 0; j < 4; ++j)                                              \
        bfr[NXT][j] = *(const bf16x8*)(Bn_ + rdB + j * 512);                   \
    }                                                                          \
    __builtin_amdgcn_s_setprio(1);                                             \
    _Pragma("unroll")                                                          \
    for (int i = 0; i < 4; ++i)                                                \
      _Pragma("unroll")                                                        \
      for (int j = 0; j < 4; ++j)                                              \
        acc[4 + i][j] = __builtin_amdgcn_mfma_f32_16x16x32_bf16(aHi[i],        \
                          bfr[CUR][j], acc[4 + i][j], 0, 0, 0);                \
    __builtin_amdgcn_s_setprio(0);                                             \
  }

  // main loop: steady-state vmcnt(6) (A/B(s+2) + A(s+3) in flight)
  for (int s = 0; s < NS - 4; s += 2) {
    SLICE_BODY(s,     0, 1, true, true, 6, true);
    SLICE_BODY(s + 1, 1, 0, true, true, 6, true);
  }
  // tail: slices NS-4 .. NS-1
  SLICE_BODY(NS - 4, 0, 1, true,  true,  6, true);   // stages slice NS-1
  SLICE_BODY(NS - 3, 1, 0, false, false, 4, true);
  SLICE_BODY(NS - 2, 0, 1, false, false, 0, true);
  SLICE_BODY(NS - 1, 1, 0, false, false, 0, false);
#undef SLICE_BODY

  // epilogue: C/D layout col=lane&15, row=(lane>>4)*4+reg
  const int cr = (lane >> 4) << 2;
#pragma unroll
  for (int fr = 0; fr < 8; ++fr) {
    int row = brow + (wm << 7) + fr * 16 + cr;
#pragma unroll
    for (int fc = 0; fc < 4; ++fc) {
      int col = bcol + (wn << 6) + fc * 16 + (lane & 15);
      float bv = bias[col];
      float* cp = C + ((size_t)row << 12) + col;
#pragma unroll
      for (int r = 0; r < 4; ++r)
        cp[(size_t)r << 12] = acc[fr][fc][r] + bv;
    }
  }
}

extern "C" void kernel_launch(void* const* d_in, const int* in_sizes, int n_in,
                              void* d_out, int out_size, void* d_ws, size_t ws_size,
                              hipStream_t stream) {
  const float* x     = (const float*)d_in[0];
  const float* psi   = (const float*)d_in[1];
  const float* omega = (const float*)d_in[2];
  const float* g     = (const float*)d_in[3];
  const float* bias  = (const float*)d_in[4];

  const int M = in_sizes[0] / DFEAT;   // 8192
  const int N = DFEAT;
  const int K = DFEAT;

  unsigned short* Wt = (unsigned short*)d_ws;                              // 32 MB
  unsigned short* Xb = (unsigned short*)((char*)d_ws + (size_t)N * K * 2); // 64 MB

  build_wt_kernel<<<DFEAT, 256, 0, stream>>>(psi, omega, g, Wt);

  int n8 = (M * K) / 8;
  convert_x_kernel<<<2048, 256, 0, stream>>>(x, Xb, n8);

  int nwg = (M / 256) * (N / 256);   // 32*16 = 512, divisible by 8
  gemm_kernel<<<nwg, 512, 0, stream>>>(Xb, Wt, bias, (float*)d_out, M);
}